// Round 20
// baseline (192.775 us; speedup 1.0000x reference)
//
#include <hip/hip_runtime.h>
#include <hip/hip_bf16.h>

#define EMB_D   768
#define N_SLOTS 16
#define KEY_D   64
#define N_ITER  3
#define BS      128
#define N_TOK   196
#define N_ROWS  (BS * N_TOK)      // 25088
#define PROMPT_N (5 * 8 * EMB_D)  // 30720
#define TOT_SLOT_ROWS (BS * N_SLOTS) // 2048

typedef __attribute__((ext_vector_type(8))) short bf16x8;
typedef __attribute__((ext_vector_type(4))) float f32x4;

__device__ __forceinline__ float sigmoid_f(float x) { return 1.f / (1.f + __expf(-x)); }
__device__ __forceinline__ float tanh_f(float x)    { return 1.f - 2.f / (__expf(2.f * x) + 1.f); }
__device__ __forceinline__ short f2bf(float f) {
    __hip_bfloat16 h = __float2bfloat16(f);
    return *reinterpret_cast<short*>(&h);
}
__device__ __forceinline__ float bf2f(short s) {
    return __int_as_float(((int)(unsigned short)s) << 16);
}
__device__ __forceinline__ float dot4(float4 a, float4 b) {
    return a.x * b.x + a.y * b.y + a.z * b.z + a.w * b.w;
}

// ---------------------------------------------------------------------------
// Kernel PREP (merged): WT (384 blk) | WB (144 blk) | PT (120 blk)
// ---------------------------------------------------------------------------
#define WT_BLKS 384
#define WB_BLKS 144
#define PT_BLKS 120
__global__ __launch_bounds__(256) void prep_kernel(
    const float* __restrict__ Wk, const float* __restrict__ Wv,
    const float* __restrict__ W_ih, const float* __restrict__ W_hh,
    const float* __restrict__ W1, const float* __restrict__ W2,
    const float* __restrict__ Wq, const float* __restrict__ s2p,
    short* __restrict__ WT, short* __restrict__ WB, short* __restrict__ PT)
{
    const int blk = blockIdx.x;
    if (blk < WT_BLKS) {
        const int idx = blk * 256 + threadIdx.x;
        const int n = idx / 768, k = idx % 768;
        const float v = (n < 64) ? Wk[(size_t)k * 64 + n] : Wv[(size_t)k * 64 + (n - 64)];
        WT[idx] = f2bf(v);
    } else if (blk < WT_BLKS + WB_BLKS) {
        const int idx = (blk - WT_BLKS) * 256 + threadIdx.x;
        const int row = idx >> 6, d = idx & 63;
        float v;
        if      (row < 192) v = W_ih[(size_t)row * 64 + d];
        else if (row < 384) v = W_hh[(size_t)(row - 192) * 64 + d];
        else if (row < 448) v = W1[(size_t)(row - 384) * 64 + d];
        else if (row < 512) v = W2[(size_t)(row - 448) * 64 + d];
        else                v = Wq[(size_t)d * 64 + (row - 512)];   // WqT[o][i]
        WB[idx] = f2bf(v);
    } else {
        const int n = (blk - WT_BLKS - WB_BLKS) * 256 + threadIdx.x;
        short o[64];
        #pragma unroll
        for (int h = 0; h < 64; ++h)
            o[h] = f2bf(s2p[(size_t)h * PROMPT_N + n]);
        short* op = PT + (size_t)n * 64;
        #pragma unroll
        for (int j = 0; j < 8; ++j)
            *(bf16x8*)&op[j * 8] = *(const bf16x8*)&o[j * 8];
    }
}

// ---------------------------------------------------------------------------
// Kernel A1: fbuf[row][k] = bf16( LN(features[row])[k] )  (one row per wave)
// ---------------------------------------------------------------------------
__global__ __launch_bounds__(256) void ln_bf16_kernel(
    const float* __restrict__ feat, const float* __restrict__ lnw,
    const float* __restrict__ lnb, short* __restrict__ fbuf)
{
    const int wave = threadIdx.x >> 6, lane = threadIdx.x & 63;
    const int row = blockIdx.x * 4 + wave;
    const float* fr = feat + (size_t)row * EMB_D + lane * 12;

    float x[12];
    #pragma unroll
    for (int j = 0; j < 3; ++j)
        *(float4*)&x[j * 4] = *(const float4*)&fr[j * 4];

    float s = 0.f, ss = 0.f;
    #pragma unroll
    for (int j = 0; j < 12; ++j) { s += x[j]; ss += x[j] * x[j]; }
    #pragma unroll
    for (int m = 32; m >= 1; m >>= 1) { s += __shfl_xor(s, m, 64); ss += __shfl_xor(ss, m, 64); }
    const float mean = s * (1.f / EMB_D);
    const float rstd = rsqrtf(ss * (1.f / EMB_D) - mean * mean + 1e-5f);

    const float* wp = lnw + lane * 12;
    const float* bp = lnb + lane * 12;
    short o[12];
    #pragma unroll
    for (int j = 0; j < 12; ++j)
        o[j] = f2bf((x[j] - mean) * rstd * wp[j] + bp[j]);

    short* op = fbuf + (size_t)row * EMB_D + lane * 12;
    #pragma unroll
    for (int j = 0; j < 3; ++j)
        *(short4*)&op[j * 4] = *(const short4*)&o[j * 4];
}

// ---------------------------------------------------------------------------
// Kernel A2: [kbuf|vbuf] = fbuf @ WT^T via MFMA bf16 (64-row blocks).
// LDS-transposed epilogue -> 4-row x 256 B float4 store segments.
// ---------------------------------------------------------------------------
__global__ __launch_bounds__(256) void kvgemm_kernel(
    const short* __restrict__ fbuf, const short* __restrict__ WT,
    float* __restrict__ kbuf, float* __restrict__ vbuf)
{
    __shared__ float stg[4][32][68];   // 34.8 KB; per-wave-private tiles
    const int t = threadIdx.x;
    const int wave = t >> 6, lane = t & 63;
    const int rowbase = blockIdx.x * 64 + (wave & 1) * 32;
    const int colbase = (wave >> 1) * 64;
    const int lrow = lane & 15, lk = (lane >> 4) * 8;

    f32x4 acc[2][4];
    #pragma unroll
    for (int m = 0; m < 2; ++m)
        #pragma unroll
        for (int c = 0; c < 4; ++c)
            acc[m][c] = (f32x4){0.f, 0.f, 0.f, 0.f};

    const short* a0 = fbuf + (size_t)(rowbase + lrow) * EMB_D + lk;
    const short* a1 = a0 + 16 * EMB_D;
    const short* bp = WT + (size_t)(colbase + lrow) * EMB_D + lk;

    #pragma unroll 2
    for (int k0 = 0; k0 < EMB_D; k0 += 32) {
        const bf16x8 af0 = *(const bf16x8*)(a0 + k0);
        const bf16x8 af1 = *(const bf16x8*)(a1 + k0);
        #pragma unroll
        for (int c = 0; c < 4; ++c) {
            const bf16x8 bf = *(const bf16x8*)(bp + (size_t)c * 16 * EMB_D + k0);
            acc[0][c] = __builtin_amdgcn_mfma_f32_16x16x32_bf16(af0, bf, acc[0][c], 0, 0, 0);
            acc[1][c] = __builtin_amdgcn_mfma_f32_16x16x32_bf16(af1, bf, acc[1][c], 0, 0, 0);
        }
    }

    // stage wave tile (32 rows x 64 cols) into LDS
    const int dn = lane & 15;
    const int dm0 = (lane >> 4) * 4;
    #pragma unroll
    for (int m = 0; m < 2; ++m)
        #pragma unroll
        for (int c = 0; c < 4; ++c)
            #pragma unroll
            for (int r = 0; r < 4; ++r)
                stg[wave][m * 16 + dm0 + r][c * 16 + dn] = acc[m][c][r];
    // wave-private: compiler inserts lgkmcnt before readback

    // coalesced writeback: 4 rows x 256 B per instruction
    float* outp = ((wave >> 1) == 0) ? kbuf : vbuf;
    const int rrow = lane >> 4;          // 0..3
    const int c4 = (lane & 15) * 4;      // 0..60
    #pragma unroll
    for (int p = 0; p < 8; ++p) {
        const int row = p * 4 + rrow;
        *(float4*)&outp[(size_t)(rowbase + row) * 64 + c4] =
            *(const float4*)&stg[wave][row][c4];
    }
}

// ---------------------------------------------------------------------------
// Kernel B (mega v2): 3 slot-attention iterations per batch; small matmuls
// via MFMA (WB weights, L2-hot); softmax merged into logits (shfl).
// ---------------------------------------------------------------------------
__global__ __launch_bounds__(512) void slot_iter_kernel(
    const float* __restrict__ kbuf, const float* __restrict__ vbuf,
    const short* __restrict__ WB,
    const float* __restrict__ noise, const float* __restrict__ mu,
    const float* __restrict__ sigma,
    const float* __restrict__ lnsw, const float* __restrict__ lnsb,
    const float* __restrict__ lnow, const float* __restrict__ lnob,
    const float* __restrict__ b_ih, const float* __restrict__ b_hh,
    const float* __restrict__ b1, const float* __restrict__ b2,
    short* __restrict__ slotsB)
{
    __shared__ float k_l[N_TOK][68];
    __shared__ short v_l[N_TOK][68];
    __shared__ float att[N_TOK][17];
    __shared__ float slots[16][68];
    __shared__ float snew[16][68];
    __shared__ float q_l[16][68];
    __shared__ float gi_l[16][204];
    __shared__ float gh_l[16][204];
    __shared__ float csp[32][17];
    __shared__ float cs_inv[16];
    __shared__ short lnb_bf[16][72];
    __shared__ short upd_bf[16][72];
    __shared__ short slots_bf[16][72];
    __shared__ short mlp_bf[16][72];

    const int b = blockIdx.x, t = threadIdx.x;
    const int wv = t >> 6, lane = t & 63;
    const int l15 = lane & 15, lk8 = (lane >> 4) * 8;
    const int dr0 = (lane >> 4) * 4;

    // ---- stage K (f32) + V (bf16) ----
    {
        const float* kb = kbuf + (size_t)b * N_TOK * 64;
        const float* vb = vbuf + (size_t)b * N_TOK * 64;
        for (int i4 = t; i4 < N_TOK * 16; i4 += 512) {
            const int r = i4 >> 4, c4 = (i4 & 15) * 4;
            *(float4*)&k_l[r][c4] = *(const float4*)&kb[r * 64 + c4];
            const float4 vx = *(const float4*)&vb[r * 64 + c4];
            short4 vs;
            vs.x = f2bf(vx.x); vs.y = f2bf(vx.y); vs.z = f2bf(vx.z); vs.w = f2bf(vx.w);
            *(short4*)&v_l[r][c4] = vs;
        }
    }

    // ---- init slots (f32 + bf16) and LN_slot -> lnb_bf ----
    if (t < 256) {
        const int s = t >> 4, d0 = (t & 15) * 4;
        const float4 nz = *(const float4*)&noise[((size_t)b * 16 + s) * 64 + d0];
        float x[4];
        x[0] = nz.x * sigma[d0 + 0] + mu[d0 + 0];
        x[1] = nz.y * sigma[d0 + 1] + mu[d0 + 1];
        x[2] = nz.z * sigma[d0 + 2] + mu[d0 + 2];
        x[3] = nz.w * sigma[d0 + 3] + mu[d0 + 3];
        #pragma unroll
        for (int k = 0; k < 4; ++k) {
            slots[s][d0 + k] = x[k];
            slots_bf[s][d0 + k] = f2bf(x[k]);
        }
        float sum = x[0] + x[1] + x[2] + x[3];
        float ssm = x[0]*x[0] + x[1]*x[1] + x[2]*x[2] + x[3]*x[3];
        #pragma unroll
        for (int m = 8; m >= 1; m >>= 1) { sum += __shfl_xor(sum, m, 64); ssm += __shfl_xor(ssm, m, 64); }
        const float mean = sum * (1.f / 64);
        const float rstd = rsqrtf(ssm * (1.f / 64) - mean * mean + 1e-5f);
        #pragma unroll
        for (int k = 0; k < 4; ++k)
            lnb_bf[s][d0 + k] = f2bf((x[k] - mean) * rstd * lnsw[d0 + k] + lnsb[d0 + k]);
    }
    __syncthreads();

    // ---- q0 via MFMA (waves 0-3) ----
    if (wv < 4) {
        const short* ar = &lnb_bf[l15][lk8];
        const short* br = WB + (size_t)(512 + wv * 16 + l15) * 64 + lk8;
        f32x4 acc = (f32x4){0.f, 0.f, 0.f, 0.f};
        acc = __builtin_amdgcn_mfma_f32_16x16x32_bf16(*(const bf16x8*)ar,
              *(const bf16x8*)br, acc, 0, 0, 0);
        acc = __builtin_amdgcn_mfma_f32_16x16x32_bf16(*(const bf16x8*)(ar + 32),
              *(const bf16x8*)(br + 32), acc, 0, 0, 0);
        const int col = wv * 16 + l15;
        #pragma unroll
        for (int r = 0; r < 4; ++r) q_l[dr0 + r][col] = acc[r] * 0.125f;
    }
    __syncthreads();

    for (int it = 0; it < N_ITER; ++it) {
        // ---- logits + softmax(shfl) + cs partials ----
        {
            const int s = t & 15, ng = t >> 4;
            float4 q4[16];
            #pragma unroll
            for (int dq = 0; dq < 16; ++dq) q4[dq] = *(const float4*)&q_l[s][dq * 4];
            float psum = 0.f;
            #pragma unroll
            for (int i = 0; i < 7; ++i) {
                const int n = ng + 32 * i;
                if (n < N_TOK) {
                    float a = 0.f;
                    #pragma unroll
                    for (int dq = 0; dq < 16; ++dq)
                        a += dot4(*(const float4*)&k_l[n][dq * 4], q4[dq]);
                    float mx = a;
                    #pragma unroll
                    for (int mm = 1; mm < 16; mm <<= 1) mx = fmaxf(mx, __shfl_xor(mx, mm, 64));
                    const float e = __expf(a - mx);
                    float sm = e;
                    #pragma unroll
                    for (int mm = 1; mm < 16; mm <<= 1) sm += __shfl_xor(sm, mm, 64);
                    const float av = e / sm + 1e-8f;
                    att[n][s] = av;
                    psum += av;
                }
            }
            csp[ng][s] = psum;
        }
        __syncthreads();
        if (t < 16) {
            float cs = 0.f;
            #pragma unroll
            for (int ng = 0; ng < 32; ++ng) cs += csp[ng][t];
            cs_inv[t] = 1.f / cs;
        }
        __syncthreads();

        // ---- upd (bf16 out) ----
        {
            const int d2 = (t & 31) * 2, s = t >> 5;
            float a0 = 0.f, a1 = 0.f;
            #pragma unroll 4
            for (int n = 0; n < N_TOK; ++n) {
                const float an = att[n][s];
                const short2 v2 = *(const short2*)&v_l[n][d2];
                a0 = fmaf(an, bf2f(v2.x), a0);
                a1 = fmaf(an, bf2f(v2.y), a1);
            }
            const float ci = cs_inv[s];
            upd_bf[s][d2]     = f2bf(a0 * ci);
            upd_bf[s][d2 + 1] = f2bf(a1 * ci);
        }
        __syncthreads();

        // ---- GRU gates via MFMA: 24 tiles over 8 waves ----
        {
            #pragma unroll
            for (int u = wv; u < 24; u += 8) {
                const int isgh = (u >= 12);
                const int tile = isgh ? u - 12 : u;
                const short* ar = isgh ? &slots_bf[l15][lk8] : &upd_bf[l15][lk8];
                const short* br = WB + (size_t)(isgh * 192 + tile * 16 + l15) * 64 + lk8;
                f32x4 acc = (f32x4){0.f, 0.f, 0.f, 0.f};
                acc = __builtin_amdgcn_mfma_f32_16x16x32_bf16(*(const bf16x8*)ar,
                      *(const bf16x8*)br, acc, 0, 0, 0);
                acc = __builtin_amdgcn_mfma_f32_16x16x32_bf16(*(const bf16x8*)(ar + 32),
                      *(const bf16x8*)(br + 32), acc, 0, 0, 0);
                float* dst = isgh ? &gh_l[0][0] : &gi_l[0][0];
                const int col = tile * 16 + l15;
                #pragma unroll
                for (int r = 0; r < 4; ++r) dst[(dr0 + r) * 204 + col] = acc[r];
            }
        }
        __syncthreads();

        // ---- combine gates -> snew ----
        if (t < 256) {
            const int s = t >> 4, d0 = t & 15;
            #pragma unroll
            for (int m = 0; m < 4; ++m) {
                const int d = d0 + 16 * m;
                const float r  = sigmoid_f(gi_l[s][d] + b_ih[d] + gh_l[s][d] + b_hh[d]);
                const float z  = sigmoid_f(gi_l[s][64 + d] + b_ih[64 + d] + gh_l[s][64 + d] + b_hh[64 + d]);
                const float nc = tanh_f(gi_l[s][128 + d] + b_ih[128 + d]
                                        + r * (gh_l[s][128 + d] + b_hh[128 + d]));
                snew[s][d] = (1.f - z) * nc + z * slots[s][d];
            }
        }
        __syncthreads();

        // ---- LN_out(snew) -> lnb_bf ----
        if (t < 256) {
            const int s = t >> 4, d0 = (t & 15) * 4;
            const float4 x = *(const float4*)&snew[s][d0];
            float sum = x.x + x.y + x.z + x.w;
            float ssm = x.x*x.x + x.y*x.y + x.z*x.z + x.w*x.w;
            #pragma unroll
            for (int m = 8; m >= 1; m >>= 1) { sum += __shfl_xor(sum, m, 64); ssm += __shfl_xor(ssm, m, 64); }
            const float mean = sum * (1.f / 64);
            const float rstd = rsqrtf(ssm * (1.f / 64) - mean * mean + 1e-5f);
            lnb_bf[s][d0 + 0] = f2bf((x.x - mean) * rstd * lnow[d0 + 0] + lnob[d0 + 0]);
            lnb_bf[s][d0 + 1] = f2bf((x.y - mean) * rstd * lnow[d0 + 1] + lnob[d0 + 1]);
            lnb_bf[s][d0 + 2] = f2bf((x.z - mean) * rstd * lnow[d0 + 2] + lnob[d0 + 2]);
            lnb_bf[s][d0 + 3] = f2bf((x.w - mean) * rstd * lnow[d0 + 3] + lnob[d0 + 3]);
        }
        __syncthreads();

        // ---- mlp1 via MFMA ----
        if (wv < 4) {
            const short* ar = &lnb_bf[l15][lk8];
            const short* br = WB + (size_t)(384 + wv * 16 + l15) * 64 + lk8;
            f32x4 acc = (f32x4){0.f, 0.f, 0.f, 0.f};
            acc = __builtin_amdgcn_mfma_f32_16x16x32_bf16(*(const bf16x8*)ar,
                  *(const bf16x8*)br, acc, 0, 0, 0);
            acc = __builtin_amdgcn_mfma_f32_16x16x32_bf16(*(const bf16x8*)(ar + 32),
                  *(const bf16x8*)(br + 32), acc, 0, 0, 0);
            const int col = wv * 16 + l15;
            const float bb = b1[col];
            #pragma unroll
            for (int r = 0; r < 4; ++r)
                mlp_bf[dr0 + r][col] = f2bf(fmaxf(acc[r] + bb, 0.f));
        }
        __syncthreads();

        // ---- mlp2 via MFMA: slots = snew + mlp@W2^T + b2 ----
        if (wv < 4) {
            const short* ar = &mlp_bf[l15][lk8];
            const short* br = WB + (size_t)(448 + wv * 16 + l15) * 64 + lk8;
            f32x4 acc = (f32x4){0.f, 0.f, 0.f, 0.f};
            acc = __builtin_amdgcn_mfma_f32_16x16x32_bf16(*(const bf16x8*)ar,
                  *(const bf16x8*)br, acc, 0, 0, 0);
            acc = __builtin_amdgcn_mfma_f32_16x16x32_bf16(*(const bf16x8*)(ar + 32),
                  *(const bf16x8*)(br + 32), acc, 0, 0, 0);
            const int col = wv * 16 + l15;
            const float bb = b2[col];
            #pragma unroll
            for (int r = 0; r < 4; ++r) {
                const float v = snew[dr0 + r][col] + acc[r] + bb;
                slots[dr0 + r][col] = v;
                slots_bf[dr0 + r][col] = f2bf(v);
            }
        }
        __syncthreads();

        if (it < N_ITER - 1) {
            if (t < 256) {
                const int s = t >> 4, d0 = (t & 15) * 4;
                const float4 x = *(const float4*)&slots[s][d0];
                float sum = x.x + x.y + x.z + x.w;
                float ssm = x.x*x.x + x.y*x.y + x.z*x.z + x.w*x.w;
                #pragma unroll
                for (int m = 8; m >= 1; m >>= 1) { sum += __shfl_xor(sum, m, 64); ssm += __shfl_xor(ssm, m, 64); }
                const float mean = sum * (1.f / 64);
                const float rstd = rsqrtf(ssm * (1.f / 64) - mean * mean + 1e-5f);
                lnb_bf[s][d0 + 0] = f2bf((x.x - mean) * rstd * lnsw[d0 + 0] + lnsb[d0 + 0]);
                lnb_bf[s][d0 + 1] = f2bf((x.y - mean) * rstd * lnsw[d0 + 1] + lnsb[d0 + 1]);
                lnb_bf[s][d0 + 2] = f2bf((x.z - mean) * rstd * lnsw[d0 + 2] + lnsb[d0 + 2]);
                lnb_bf[s][d0 + 3] = f2bf((x.w - mean) * rstd * lnsw[d0 + 3] + lnsb[d0 + 3]);
            }
            __syncthreads();
            if (wv < 4) {
                const short* ar = &lnb_bf[l15][lk8];
                const short* br = WB + (size_t)(512 + wv * 16 + l15) * 64 + lk8;
                f32x4 acc = (f32x4){0.f, 0.f, 0.f, 0.f};
                acc = __builtin_amdgcn_mfma_f32_16x16x32_bf16(*(const bf16x8*)ar,
                      *(const bf16x8*)br, acc, 0, 0, 0);
                acc = __builtin_amdgcn_mfma_f32_16x16x32_bf16(*(const bf16x8*)(ar + 32),
                      *(const bf16x8*)(br + 32), acc, 0, 0, 0);
                const int col = wv * 16 + l15;
                #pragma unroll
                for (int r = 0; r < 4; ++r) q_l[dr0 + r][col] = acc[r] * 0.125f;
            }
            __syncthreads();
        }
    }

    // ---- final: slotsB = slots_bf ----
    for (int idx = t; idx < 1024; idx += 512)
        slotsB[(size_t)b * 1024 + idx] = slots_bf[idx >> 6][idx & 63];
}

// ---------------------------------------------------------------------------
// Kernel D: prompts = PT @ slotsB^T via MFMA. LDS-transposed; REGULAR stores
// (A/B vs NT: round-18 FETCH~=WRITE suggests NT partial-line RMW at HBM).
// ---------------------------------------------------------------------------
__global__ __launch_bounds__(256) void prompt_mfma_kernel(
    const short* __restrict__ slotsB, const short* __restrict__ PT,
    float* __restrict__ out)
{
    __shared__ float stg[4][16][132];
    const int wave = threadIdx.x >> 6, lane = threadIdx.x & 63;
    const int rowblk = blockIdx.x & 127;
    const int colblk = blockIdx.x >> 7;
    const int rowbase = rowblk * 16;
    const int colbase = colblk * 512 + wave * 128;
    const int l15 = lane & 15, lk = (lane >> 4) * 8;

    const short* bp = slotsB + (size_t)(rowbase + l15) * 64 + lk;
    const bf16x8 b0 = *(const bf16x8*)bp;
    const bf16x8 b1 = *(const bf16x8*)(bp + 32);

    f32x4 acc[8];
    #pragma unroll
    for (int c = 0; c < 8; ++c) {
        const short* ap = PT + (size_t)(colbase + c * 16 + l15) * 64 + lk;
        const bf16x8 a0 = *(const bf16x8*)ap;
        const bf16x8 a1 = *(const bf16x8*)(ap + 32);
        acc[c] = (f32x4){0.f, 0.f, 0.f, 0.f};
        acc[c] = __builtin_amdgcn_mfma_f32_16x16x32_bf16(a0, b0, acc[c], 0, 0, 0);
        acc[c] = __builtin_amdgcn_mfma_f32_16x16x32_bf16(a1, b1, acc[c], 0, 0, 0);
    }

    const int nofs = (lane >> 4) * 4;
    #pragma unroll
    for (int c = 0; c < 8; ++c)
        *(f32x4*)&stg[wave][l15][c * 16 + nofs] = acc[c];

    const int rrow = lane >> 5;
    const int chunk = lane & 31;
    #pragma unroll
    for (int p = 0; p < 8; ++p) {
        const int row = p * 2 + rrow;
        const f32x4 v = *(const f32x4*)&stg[wave][row][chunk * 4];
        *(f32x4*)&out[(size_t)(rowbase + row) * PROMPT_N + colbase + chunk * 4] = v;
    }
}

// ---------------------------------------------------------------------------
extern "C" void kernel_launch(void* const* d_in, const int* in_sizes, int n_in,
                              void* d_out, int out_size, void* d_ws, size_t ws_size,
                              hipStream_t stream)
{
    (void)in_sizes; (void)n_in; (void)out_size; (void)ws_size;
    const float* feat    = (const float*)d_in[0];
    const float* noise   = (const float*)d_in[1];
    const float* ln_in_w = (const float*)d_in[2];
    const float* ln_in_b = (const float*)d_in[3];
    const float* ln_s_w  = (const float*)d_in[4];
    const float* ln_s_b  = (const float*)d_in[5];
    const float* ln_o_w  = (const float*)d_in[6];
    const float* ln_o_b  = (const float*)d_in[7];
    const float* mu      = (const float*)d_in[8];
    const float* sigma   = (const float*)d_in[9];
    const float* Wk      = (const float*)d_in[10];
    const float* Wq      = (const float*)d_in[11];
    const float* Wv      = (const float*)d_in[12];
    const float* W_ih    = (const float*)d_in[13];
    const float* W_hh    = (const float*)d_in[14];
    const float* b_ih    = (const float*)d_in[15];
    const float* b_hh    = (const float*)d_in[16];
    const float* W1      = (const float*)d_in[17];
    const float* b1      = (const float*)d_in[18];
    const float* W2      = (const float*)d_in[19];
    const float* b2      = (const float*)d_in[20];
    const float* s2p     = (const float*)d_in[21];

    float* kbuf   = (float*)d_ws;                                   // 25088*64 f32
    float* vbuf   = kbuf  + (size_t)N_ROWS * 64;                    // 25088*64 f32
    short* slotsB = (short*)(vbuf + (size_t)N_ROWS * 64);           // 2048*64 bf16
    short* PT     = slotsB + (size_t)TOT_SLOT_ROWS * KEY_D;         // 30720*64 bf16
    short* fbuf   = PT + (size_t)PROMPT_N * KEY_D;                  // 25088*768 bf16
    short* WT     = fbuf + (size_t)N_ROWS * EMB_D;                  // 128*768 bf16
    short* WB     = WT + (size_t)128 * EMB_D;                       // 576*64 bf16

    hipLaunchKernelGGL(prep_kernel, dim3(WT_BLKS + WB_BLKS + PT_BLKS), dim3(256), 0, stream,
                       Wk, Wv, W_ih, W_hh, W1, W2, Wq, s2p, WT, WB, PT);
    hipLaunchKernelGGL(ln_bf16_kernel, dim3(N_ROWS / 4), dim3(256), 0, stream,
                       feat, ln_in_w, ln_in_b, fbuf);
    hipLaunchKernelGGL(kvgemm_kernel, dim3(N_ROWS / 64), dim3(256), 0, stream,
                       fbuf, WT, kbuf, vbuf);
    hipLaunchKernelGGL(slot_iter_kernel, dim3(BS), dim3(512), 0, stream,
                       kbuf, vbuf, WB, noise, mu, sigma, ln_s_w, ln_s_b,
                       ln_o_w, ln_o_b, b_ih, b_hh, b1, b2, slotsB);
    hipLaunchKernelGGL(prompt_mfma_kernel, dim3(60 * 128), dim3(256), 0, stream,
                       slotsB, PT, (float*)d_out);
}

// Round 21
// 175.586 us; speedup vs baseline: 1.0979x; 1.0979x over previous
//
#include <hip/hip_runtime.h>
#include <hip/hip_bf16.h>

#define EMB_D   768
#define N_SLOTS 16
#define KEY_D   64
#define N_ITER  3
#define BS      128
#define N_TOK   196
#define N_ROWS  (BS * N_TOK)      // 25088
#define PROMPT_N (5 * 8 * EMB_D)  // 30720
#define TOT_SLOT_ROWS (BS * N_SLOTS) // 2048

typedef __attribute__((ext_vector_type(8))) short bf16x8;
typedef __attribute__((ext_vector_type(4))) float f32x4;

__device__ __forceinline__ float sigmoid_f(float x) { return 1.f / (1.f + __expf(-x)); }
__device__ __forceinline__ float tanh_f(float x)    { return 1.f - 2.f / (__expf(2.f * x) + 1.f); }
__device__ __forceinline__ short f2bf(float f) {
    __hip_bfloat16 h = __float2bfloat16(f);
    return *reinterpret_cast<short*>(&h);
}
__device__ __forceinline__ float bf2f(short s) {
    return __int_as_float(((int)(unsigned short)s) << 16);
}
__device__ __forceinline__ float dot4(float4 a, float4 b) {
    return a.x * b.x + a.y * b.y + a.z * b.z + a.w * b.w;
}

// ---------------------------------------------------------------------------
// Kernel PREP (merged): WT (384 blk) | WB (144 blk) | PT (120 blk)
// ---------------------------------------------------------------------------
#define WT_BLKS 384
#define WB_BLKS 144
#define PT_BLKS 120
__global__ __launch_bounds__(256) void prep_kernel(
    const float* __restrict__ Wk, const float* __restrict__ Wv,
    const float* __restrict__ W_ih, const float* __restrict__ W_hh,
    const float* __restrict__ W1, const float* __restrict__ W2,
    const float* __restrict__ Wq, const float* __restrict__ s2p,
    short* __restrict__ WT, short* __restrict__ WB, short* __restrict__ PT)
{
    const int blk = blockIdx.x;
    if (blk < WT_BLKS) {
        const int idx = blk * 256 + threadIdx.x;
        const int n = idx / 768, k = idx % 768;
        const float v = (n < 64) ? Wk[(size_t)k * 64 + n] : Wv[(size_t)k * 64 + (n - 64)];
        WT[idx] = f2bf(v);
    } else if (blk < WT_BLKS + WB_BLKS) {
        const int idx = (blk - WT_BLKS) * 256 + threadIdx.x;
        const int row = idx >> 6, d = idx & 63;
        float v;
        if      (row < 192) v = W_ih[(size_t)row * 64 + d];
        else if (row < 384) v = W_hh[(size_t)(row - 192) * 64 + d];
        else if (row < 448) v = W1[(size_t)(row - 384) * 64 + d];
        else if (row < 512) v = W2[(size_t)(row - 448) * 64 + d];
        else                v = Wq[(size_t)d * 64 + (row - 512)];   // WqT[o][i]
        WB[idx] = f2bf(v);
    } else {
        const int n = (blk - WT_BLKS - WB_BLKS) * 256 + threadIdx.x;
        short o[64];
        #pragma unroll
        for (int h = 0; h < 64; ++h)
            o[h] = f2bf(s2p[(size_t)h * PROMPT_N + n]);
        short* op = PT + (size_t)n * 64;
        #pragma unroll
        for (int j = 0; j < 8; ++j)
            *(bf16x8*)&op[j * 8] = *(const bf16x8*)&o[j * 8];
    }
}

// ---------------------------------------------------------------------------
// Kernel A1: fbuf[row][k] = bf16( LN(features[row])[k] )  (one row per wave)
// ---------------------------------------------------------------------------
__global__ __launch_bounds__(256) void ln_bf16_kernel(
    const float* __restrict__ feat, const float* __restrict__ lnw,
    const float* __restrict__ lnb, short* __restrict__ fbuf)
{
    const int wave = threadIdx.x >> 6, lane = threadIdx.x & 63;
    const int row = blockIdx.x * 4 + wave;
    const float* fr = feat + (size_t)row * EMB_D + lane * 12;

    float x[12];
    #pragma unroll
    for (int j = 0; j < 3; ++j)
        *(float4*)&x[j * 4] = *(const float4*)&fr[j * 4];

    float s = 0.f, ss = 0.f;
    #pragma unroll
    for (int j = 0; j < 12; ++j) { s += x[j]; ss += x[j] * x[j]; }
    #pragma unroll
    for (int m = 32; m >= 1; m >>= 1) { s += __shfl_xor(s, m, 64); ss += __shfl_xor(ss, m, 64); }
    const float mean = s * (1.f / EMB_D);
    const float rstd = rsqrtf(ss * (1.f / EMB_D) - mean * mean + 1e-5f);

    const float* wp = lnw + lane * 12;
    const float* bp = lnb + lane * 12;
    short o[12];
    #pragma unroll
    for (int j = 0; j < 12; ++j)
        o[j] = f2bf((x[j] - mean) * rstd * wp[j] + bp[j]);

    short* op = fbuf + (size_t)row * EMB_D + lane * 12;
    #pragma unroll
    for (int j = 0; j < 3; ++j)
        *(short4*)&op[j * 4] = *(const short4*)&o[j * 4];
}

// ---------------------------------------------------------------------------
// Kernel A2: [kbuf|vbuf] = fbuf @ WT^T via MFMA bf16 (64-row blocks).
// LDS-transposed epilogue -> 4-row x 256 B float4 store segments.
// ---------------------------------------------------------------------------
__global__ __launch_bounds__(256) void kvgemm_kernel(
    const short* __restrict__ fbuf, const short* __restrict__ WT,
    float* __restrict__ kbuf, float* __restrict__ vbuf)
{
    __shared__ float stg[4][32][68];   // 34.8 KB; per-wave-private tiles
    const int t = threadIdx.x;
    const int wave = t >> 6, lane = t & 63;
    const int rowbase = blockIdx.x * 64 + (wave & 1) * 32;
    const int colbase = (wave >> 1) * 64;
    const int lrow = lane & 15, lk = (lane >> 4) * 8;

    f32x4 acc[2][4];
    #pragma unroll
    for (int m = 0; m < 2; ++m)
        #pragma unroll
        for (int c = 0; c < 4; ++c)
            acc[m][c] = (f32x4){0.f, 0.f, 0.f, 0.f};

    const short* a0 = fbuf + (size_t)(rowbase + lrow) * EMB_D + lk;
    const short* a1 = a0 + 16 * EMB_D;
    const short* bp = WT + (size_t)(colbase + lrow) * EMB_D + lk;

    #pragma unroll 2
    for (int k0 = 0; k0 < EMB_D; k0 += 32) {
        const bf16x8 af0 = *(const bf16x8*)(a0 + k0);
        const bf16x8 af1 = *(const bf16x8*)(a1 + k0);
        #pragma unroll
        for (int c = 0; c < 4; ++c) {
            const bf16x8 bf = *(const bf16x8*)(bp + (size_t)c * 16 * EMB_D + k0);
            acc[0][c] = __builtin_amdgcn_mfma_f32_16x16x32_bf16(af0, bf, acc[0][c], 0, 0, 0);
            acc[1][c] = __builtin_amdgcn_mfma_f32_16x16x32_bf16(af1, bf, acc[1][c], 0, 0, 0);
        }
    }

    // stage wave tile (32 rows x 64 cols) into LDS
    const int dn = lane & 15;
    const int dm0 = (lane >> 4) * 4;
    #pragma unroll
    for (int m = 0; m < 2; ++m)
        #pragma unroll
        for (int c = 0; c < 4; ++c)
            #pragma unroll
            for (int r = 0; r < 4; ++r)
                stg[wave][m * 16 + dm0 + r][c * 16 + dn] = acc[m][c][r];
    // wave-private: compiler inserts lgkmcnt before readback

    // coalesced writeback: 4 rows x 256 B per instruction
    float* outp = ((wave >> 1) == 0) ? kbuf : vbuf;
    const int rrow = lane >> 4;          // 0..3
    const int c4 = (lane & 15) * 4;      // 0..60
    #pragma unroll
    for (int p = 0; p < 8; ++p) {
        const int row = p * 4 + rrow;
        *(float4*)&outp[(size_t)(rowbase + row) * 64 + c4] =
            *(const float4*)&stg[wave][row][c4];
    }
}

// ---------------------------------------------------------------------------
// Kernel B (mega v2): 3 slot-attention iterations per batch; small matmuls
// via MFMA (WB weights, L2-hot); softmax merged into logits (shfl).
// ---------------------------------------------------------------------------
__global__ __launch_bounds__(512) void slot_iter_kernel(
    const float* __restrict__ kbuf, const float* __restrict__ vbuf,
    const short* __restrict__ WB,
    const float* __restrict__ noise, const float* __restrict__ mu,
    const float* __restrict__ sigma,
    const float* __restrict__ lnsw, const float* __restrict__ lnsb,
    const float* __restrict__ lnow, const float* __restrict__ lnob,
    const float* __restrict__ b_ih, const float* __restrict__ b_hh,
    const float* __restrict__ b1, const float* __restrict__ b2,
    short* __restrict__ slotsB)
{
    __shared__ float k_l[N_TOK][68];
    __shared__ short v_l[N_TOK][68];
    __shared__ float att[N_TOK][17];
    __shared__ float slots[16][68];
    __shared__ float snew[16][68];
    __shared__ float q_l[16][68];
    __shared__ float gi_l[16][204];
    __shared__ float gh_l[16][204];
    __shared__ float csp[32][17];
    __shared__ float cs_inv[16];
    __shared__ short lnb_bf[16][72];
    __shared__ short upd_bf[16][72];
    __shared__ short slots_bf[16][72];
    __shared__ short mlp_bf[16][72];

    const int b = blockIdx.x, t = threadIdx.x;
    const int wv = t >> 6, lane = t & 63;
    const int l15 = lane & 15, lk8 = (lane >> 4) * 8;
    const int dr0 = (lane >> 4) * 4;

    // ---- stage K (f32) + V (bf16) ----
    {
        const float* kb = kbuf + (size_t)b * N_TOK * 64;
        const float* vb = vbuf + (size_t)b * N_TOK * 64;
        for (int i4 = t; i4 < N_TOK * 16; i4 += 512) {
            const int r = i4 >> 4, c4 = (i4 & 15) * 4;
            *(float4*)&k_l[r][c4] = *(const float4*)&kb[r * 64 + c4];
            const float4 vx = *(const float4*)&vb[r * 64 + c4];
            short4 vs;
            vs.x = f2bf(vx.x); vs.y = f2bf(vx.y); vs.z = f2bf(vx.z); vs.w = f2bf(vx.w);
            *(short4*)&v_l[r][c4] = vs;
        }
    }

    // ---- init slots (f32 + bf16) and LN_slot -> lnb_bf ----
    if (t < 256) {
        const int s = t >> 4, d0 = (t & 15) * 4;
        const float4 nz = *(const float4*)&noise[((size_t)b * 16 + s) * 64 + d0];
        float x[4];
        x[0] = nz.x * sigma[d0 + 0] + mu[d0 + 0];
        x[1] = nz.y * sigma[d0 + 1] + mu[d0 + 1];
        x[2] = nz.z * sigma[d0 + 2] + mu[d0 + 2];
        x[3] = nz.w * sigma[d0 + 3] + mu[d0 + 3];
        #pragma unroll
        for (int k = 0; k < 4; ++k) {
            slots[s][d0 + k] = x[k];
            slots_bf[s][d0 + k] = f2bf(x[k]);
        }
        float sum = x[0] + x[1] + x[2] + x[3];
        float ssm = x[0]*x[0] + x[1]*x[1] + x[2]*x[2] + x[3]*x[3];
        #pragma unroll
        for (int m = 8; m >= 1; m >>= 1) { sum += __shfl_xor(sum, m, 64); ssm += __shfl_xor(ssm, m, 64); }
        const float mean = sum * (1.f / 64);
        const float rstd = rsqrtf(ssm * (1.f / 64) - mean * mean + 1e-5f);
        #pragma unroll
        for (int k = 0; k < 4; ++k)
            lnb_bf[s][d0 + k] = f2bf((x[k] - mean) * rstd * lnsw[d0 + k] + lnsb[d0 + k]);
    }
    __syncthreads();

    // ---- q0 via MFMA (waves 0-3) ----
    if (wv < 4) {
        const short* ar = &lnb_bf[l15][lk8];
        const short* br = WB + (size_t)(512 + wv * 16 + l15) * 64 + lk8;
        f32x4 acc = (f32x4){0.f, 0.f, 0.f, 0.f};
        acc = __builtin_amdgcn_mfma_f32_16x16x32_bf16(*(const bf16x8*)ar,
              *(const bf16x8*)br, acc, 0, 0, 0);
        acc = __builtin_amdgcn_mfma_f32_16x16x32_bf16(*(const bf16x8*)(ar + 32),
              *(const bf16x8*)(br + 32), acc, 0, 0, 0);
        const int col = wv * 16 + l15;
        #pragma unroll
        for (int r = 0; r < 4; ++r) q_l[dr0 + r][col] = acc[r] * 0.125f;
    }
    __syncthreads();

    for (int it = 0; it < N_ITER; ++it) {
        // ---- logits + softmax(shfl) + cs partials ----
        {
            const int s = t & 15, ng = t >> 4;
            float4 q4[16];
            #pragma unroll
            for (int dq = 0; dq < 16; ++dq) q4[dq] = *(const float4*)&q_l[s][dq * 4];
            float psum = 0.f;
            #pragma unroll
            for (int i = 0; i < 7; ++i) {
                const int n = ng + 32 * i;
                if (n < N_TOK) {
                    float a = 0.f;
                    #pragma unroll
                    for (int dq = 0; dq < 16; ++dq)
                        a += dot4(*(const float4*)&k_l[n][dq * 4], q4[dq]);
                    float mx = a;
                    #pragma unroll
                    for (int mm = 1; mm < 16; mm <<= 1) mx = fmaxf(mx, __shfl_xor(mx, mm, 64));
                    const float e = __expf(a - mx);
                    float sm = e;
                    #pragma unroll
                    for (int mm = 1; mm < 16; mm <<= 1) sm += __shfl_xor(sm, mm, 64);
                    const float av = e / sm + 1e-8f;
                    att[n][s] = av;
                    psum += av;
                }
            }
            csp[ng][s] = psum;
        }
        __syncthreads();
        if (t < 16) {
            float cs = 0.f;
            #pragma unroll
            for (int ng = 0; ng < 32; ++ng) cs += csp[ng][t];
            cs_inv[t] = 1.f / cs;
        }
        __syncthreads();

        // ---- upd (bf16 out) ----
        {
            const int d2 = (t & 31) * 2, s = t >> 5;
            float a0 = 0.f, a1 = 0.f;
            #pragma unroll 4
            for (int n = 0; n < N_TOK; ++n) {
                const float an = att[n][s];
                const short2 v2 = *(const short2*)&v_l[n][d2];
                a0 = fmaf(an, bf2f(v2.x), a0);
                a1 = fmaf(an, bf2f(v2.y), a1);
            }
            const float ci = cs_inv[s];
            upd_bf[s][d2]     = f2bf(a0 * ci);
            upd_bf[s][d2 + 1] = f2bf(a1 * ci);
        }
        __syncthreads();

        // ---- GRU gates via MFMA: 24 tiles over 8 waves ----
        {
            #pragma unroll
            for (int u = wv; u < 24; u += 8) {
                const int isgh = (u >= 12);
                const int tile = isgh ? u - 12 : u;
                const short* ar = isgh ? &slots_bf[l15][lk8] : &upd_bf[l15][lk8];
                const short* br = WB + (size_t)(isgh * 192 + tile * 16 + l15) * 64 + lk8;
                f32x4 acc = (f32x4){0.f, 0.f, 0.f, 0.f};
                acc = __builtin_amdgcn_mfma_f32_16x16x32_bf16(*(const bf16x8*)ar,
                      *(const bf16x8*)br, acc, 0, 0, 0);
                acc = __builtin_amdgcn_mfma_f32_16x16x32_bf16(*(const bf16x8*)(ar + 32),
                      *(const bf16x8*)(br + 32), acc, 0, 0, 0);
                float* dst = isgh ? &gh_l[0][0] : &gi_l[0][0];
                const int col = tile * 16 + l15;
                #pragma unroll
                for (int r = 0; r < 4; ++r) dst[(dr0 + r) * 204 + col] = acc[r];
            }
        }
        __syncthreads();

        // ---- combine gates -> snew ----
        if (t < 256) {
            const int s = t >> 4, d0 = t & 15;
            #pragma unroll
            for (int m = 0; m < 4; ++m) {
                const int d = d0 + 16 * m;
                const float r  = sigmoid_f(gi_l[s][d] + b_ih[d] + gh_l[s][d] + b_hh[d]);
                const float z  = sigmoid_f(gi_l[s][64 + d] + b_ih[64 + d] + gh_l[s][64 + d] + b_hh[64 + d]);
                const float nc = tanh_f(gi_l[s][128 + d] + b_ih[128 + d]
                                        + r * (gh_l[s][128 + d] + b_hh[128 + d]));
                snew[s][d] = (1.f - z) * nc + z * slots[s][d];
            }
        }
        __syncthreads();

        // ---- LN_out(snew) -> lnb_bf ----
        if (t < 256) {
            const int s = t >> 4, d0 = (t & 15) * 4;
            const float4 x = *(const float4*)&snew[s][d0];
            float sum = x.x + x.y + x.z + x.w;
            float ssm = x.x*x.x + x.y*x.y + x.z*x.z + x.w*x.w;
            #pragma unroll
            for (int m = 8; m >= 1; m >>= 1) { sum += __shfl_xor(sum, m, 64); ssm += __shfl_xor(ssm, m, 64); }
            const float mean = sum * (1.f / 64);
            const float rstd = rsqrtf(ssm * (1.f / 64) - mean * mean + 1e-5f);
            lnb_bf[s][d0 + 0] = f2bf((x.x - mean) * rstd * lnow[d0 + 0] + lnob[d0 + 0]);
            lnb_bf[s][d0 + 1] = f2bf((x.y - mean) * rstd * lnow[d0 + 1] + lnob[d0 + 1]);
            lnb_bf[s][d0 + 2] = f2bf((x.z - mean) * rstd * lnow[d0 + 2] + lnob[d0 + 2]);
            lnb_bf[s][d0 + 3] = f2bf((x.w - mean) * rstd * lnow[d0 + 3] + lnob[d0 + 3]);
        }
        __syncthreads();

        // ---- mlp1 via MFMA ----
        if (wv < 4) {
            const short* ar = &lnb_bf[l15][lk8];
            const short* br = WB + (size_t)(384 + wv * 16 + l15) * 64 + lk8;
            f32x4 acc = (f32x4){0.f, 0.f, 0.f, 0.f};
            acc = __builtin_amdgcn_mfma_f32_16x16x32_bf16(*(const bf16x8*)ar,
                  *(const bf16x8*)br, acc, 0, 0, 0);
            acc = __builtin_amdgcn_mfma_f32_16x16x32_bf16(*(const bf16x8*)(ar + 32),
                  *(const bf16x8*)(br + 32), acc, 0, 0, 0);
            const int col = wv * 16 + l15;
            const float bb = b1[col];
            #pragma unroll
            for (int r = 0; r < 4; ++r)
                mlp_bf[dr0 + r][col] = f2bf(fmaxf(acc[r] + bb, 0.f));
        }
        __syncthreads();

        // ---- mlp2 via MFMA: slots = snew + mlp@W2^T + b2 ----
        if (wv < 4) {
            const short* ar = &mlp_bf[l15][lk8];
            const short* br = WB + (size_t)(448 + wv * 16 + l15) * 64 + lk8;
            f32x4 acc = (f32x4){0.f, 0.f, 0.f, 0.f};
            acc = __builtin_amdgcn_mfma_f32_16x16x32_bf16(*(const bf16x8*)ar,
                  *(const bf16x8*)br, acc, 0, 0, 0);
            acc = __builtin_amdgcn_mfma_f32_16x16x32_bf16(*(const bf16x8*)(ar + 32),
                  *(const bf16x8*)(br + 32), acc, 0, 0, 0);
            const int col = wv * 16 + l15;
            const float bb = b2[col];
            #pragma unroll
            for (int r = 0; r < 4; ++r) {
                const float v = snew[dr0 + r][col] + acc[r] + bb;
                slots[dr0 + r][col] = v;
                slots_bf[dr0 + r][col] = f2bf(v);
            }
        }
        __syncthreads();

        if (it < N_ITER - 1) {
            if (t < 256) {
                const int s = t >> 4, d0 = (t & 15) * 4;
                const float4 x = *(const float4*)&slots[s][d0];
                float sum = x.x + x.y + x.z + x.w;
                float ssm = x.x*x.x + x.y*x.y + x.z*x.z + x.w*x.w;
                #pragma unroll
                for (int m = 8; m >= 1; m >>= 1) { sum += __shfl_xor(sum, m, 64); ssm += __shfl_xor(ssm, m, 64); }
                const float mean = sum * (1.f / 64);
                const float rstd = rsqrtf(ssm * (1.f / 64) - mean * mean + 1e-5f);
                lnb_bf[s][d0 + 0] = f2bf((x.x - mean) * rstd * lnsw[d0 + 0] + lnsb[d0 + 0]);
                lnb_bf[s][d0 + 1] = f2bf((x.y - mean) * rstd * lnsw[d0 + 1] + lnsb[d0 + 1]);
                lnb_bf[s][d0 + 2] = f2bf((x.z - mean) * rstd * lnsw[d0 + 2] + lnsb[d0 + 2]);
                lnb_bf[s][d0 + 3] = f2bf((x.w - mean) * rstd * lnsw[d0 + 3] + lnsb[d0 + 3]);
            }
            __syncthreads();
            if (wv < 4) {
                const short* ar = &lnb_bf[l15][lk8];
                const short* br = WB + (size_t)(512 + wv * 16 + l15) * 64 + lk8;
                f32x4 acc = (f32x4){0.f, 0.f, 0.f, 0.f};
                acc = __builtin_amdgcn_mfma_f32_16x16x32_bf16(*(const bf16x8*)ar,
                      *(const bf16x8*)br, acc, 0, 0, 0);
                acc = __builtin_amdgcn_mfma_f32_16x16x32_bf16(*(const bf16x8*)(ar + 32),
                      *(const bf16x8*)(br + 32), acc, 0, 0, 0);
                const int col = wv * 16 + l15;
                #pragma unroll
                for (int r = 0; r < 4; ++r) q_l[dr0 + r][col] = acc[r] * 0.125f;
            }
            __syncthreads();
        }
    }

    // ---- final: slotsB = slots_bf ----
    for (int idx = t; idx < 1024; idx += 512)
        slotsB[(size_t)b * 1024 + idx] = slots_bf[idx >> 6][idx & 63];
}

// ---------------------------------------------------------------------------
// Kernel D: prompts = PT @ slotsB^T via MFMA. LDS-transposed, NONTEMPORAL
// 512 B-contiguous stores (confirmed best by R20 A/B: NT +17 us vs regular).
// ---------------------------------------------------------------------------
__global__ __launch_bounds__(256) void prompt_mfma_kernel(
    const short* __restrict__ slotsB, const short* __restrict__ PT,
    float* __restrict__ out)
{
    __shared__ float stg[4][16][132];
    const int wave = threadIdx.x >> 6, lane = threadIdx.x & 63;
    const int rowblk = blockIdx.x & 127;
    const int colblk = blockIdx.x >> 7;
    const int rowbase = rowblk * 16;
    const int colbase = colblk * 512 + wave * 128;
    const int l15 = lane & 15, lk = (lane >> 4) * 8;

    const short* bp = slotsB + (size_t)(rowbase + l15) * 64 + lk;
    const bf16x8 b0 = *(const bf16x8*)bp;
    const bf16x8 b1 = *(const bf16x8*)(bp + 32);

    f32x4 acc[8];
    #pragma unroll
    for (int c = 0; c < 8; ++c) {
        const short* ap = PT + (size_t)(colbase + c * 16 + l15) * 64 + lk;
        const bf16x8 a0 = *(const bf16x8*)ap;
        const bf16x8 a1 = *(const bf16x8*)(ap + 32);
        acc[c] = (f32x4){0.f, 0.f, 0.f, 0.f};
        acc[c] = __builtin_amdgcn_mfma_f32_16x16x32_bf16(a0, b0, acc[c], 0, 0, 0);
        acc[c] = __builtin_amdgcn_mfma_f32_16x16x32_bf16(a1, b1, acc[c], 0, 0, 0);
    }

    const int nofs = (lane >> 4) * 4;
    #pragma unroll
    for (int c = 0; c < 8; ++c)
        *(f32x4*)&stg[wave][l15][c * 16 + nofs] = acc[c];

    const int rrow = lane >> 5;
    const int chunk = lane & 31;
    #pragma unroll
    for (int p = 0; p < 8; ++p) {
        const int row = p * 2 + rrow;
        const f32x4 v = *(const f32x4*)&stg[wave][row][chunk * 4];
        __builtin_nontemporal_store(
            v, (f32x4*)&out[(size_t)(rowbase + row) * PROMPT_N + colbase + chunk * 4]);
    }
}

// ---------------------------------------------------------------------------
extern "C" void kernel_launch(void* const* d_in, const int* in_sizes, int n_in,
                              void* d_out, int out_size, void* d_ws, size_t ws_size,
                              hipStream_t stream)
{
    (void)in_sizes; (void)n_in; (void)out_size; (void)ws_size;
    const float* feat    = (const float*)d_in[0];
    const float* noise   = (const float*)d_in[1];
    const float* ln_in_w = (const float*)d_in[2];
    const float* ln_in_b = (const float*)d_in[3];
    const float* ln_s_w  = (const float*)d_in[4];
    const float* ln_s_b  = (const float*)d_in[5];
    const float* ln_o_w  = (const float*)d_in[6];
    const float* ln_o_b  = (const float*)d_in[7];
    const float* mu      = (const float*)d_in[8];
    const float* sigma   = (const float*)d_in[9];
    const float* Wk      = (const float*)d_in[10];
    const float* Wq      = (const float*)d_in[11];
    const float* Wv      = (const float*)d_in[12];
    const float* W_ih    = (const float*)d_in[13];
    const float* W_hh    = (const float*)d_in[14];
    const float* b_ih    = (const float*)d_in[15];
    const float* b_hh    = (const float*)d_in[16];
    const float* W1      = (const float*)d_in[17];
    const float* b1      = (const float*)d_in[18];
    const float* W2      = (const float*)d_in[19];
    const float* b2      = (const float*)d_in[20];
    const float* s2p     = (const float*)d_in[21];

    float* kbuf   = (float*)d_ws;                                   // 25088*64 f32
    float* vbuf   = kbuf  + (size_t)N_ROWS * 64;                    // 25088*64 f32
    short* slotsB = (short*)(vbuf + (size_t)N_ROWS * 64);           // 2048*64 bf16
    short* PT     = slotsB + (size_t)TOT_SLOT_ROWS * KEY_D;         // 30720*64 bf16
    short* fbuf   = PT + (size_t)PROMPT_N * KEY_D;                  // 25088*768 bf16
    short* WT     = fbuf + (size_t)N_ROWS * EMB_D;                  // 128*768 bf16
    short* WB     = WT + (size_t)128 * EMB_D;                       // 576*64 bf16

    hipLaunchKernelGGL(prep_kernel, dim3(WT_BLKS + WB_BLKS + PT_BLKS), dim3(256), 0, stream,
                       Wk, Wv, W_ih, W_hh, W1, W2, Wq, s2p, WT, WB, PT);
    hipLaunchKernelGGL(ln_bf16_kernel, dim3(N_ROWS / 4), dim3(256), 0, stream,
                       feat, ln_in_w, ln_in_b, fbuf);
    hipLaunchKernelGGL(kvgemm_kernel, dim3(N_ROWS / 64), dim3(256), 0, stream,
                       fbuf, WT, kbuf, vbuf);
    hipLaunchKernelGGL(slot_iter_kernel, dim3(BS), dim3(512), 0, stream,
                       kbuf, vbuf, WB, noise, mu, sigma, ln_s_w, ln_s_b,
                       ln_o_w, ln_o_b, b_ih, b_hh, b1, b2, slotsB);
    hipLaunchKernelGGL(prompt_mfma_kernel, dim3(60 * 128), dim3(256), 0, stream,
                       slotsB, PT, (float*)d_out);
}